// Round 3
// baseline (99.562 us; speedup 1.0000x reference)
//
#include <hip/hip_runtime.h>
#include <hip/hip_bf16.h>
#include <cstdint>
#include <cstddef>

// B=8, T=2048, D=128 causal dual-mode attention.
// logits = Qeff . K^T with Qeff[t][d] = -alpha*scale*q[t][d] + (1-alpha)*scale*q[t][(d+1)%D]
// (feature-roll moved from K onto Q). Then causal softmax, then @V.
//
// Split-KV flash decode:
//  - prepass: K->bf16, V->bf16 transposed [b][d][s], Qeff->bf16
//  - attn: 1-wave (64-thr) blocks, 32 q-rows x 4-KV-tile (256 rows) segment,
//    fragments loaded DIRECTLY from global (per-batch K/V fits XCD L2; grid x=batch
//    pins batch->XCD), no __syncthreads in the loop.
//  - combine: merges (m,l,O) partials for chunks with >1 segment.
// R3 fix: partial slot index now includes + seg (R2 raced all segments on slot0).

typedef __attribute__((ext_vector_type(8))) short short8;
typedef __attribute__((ext_vector_type(4))) float f32x4;

#define T_DIM 2048
#define D_DIM 128
#define B_DIM 8

__device__ __forceinline__ unsigned short f2bf(float f) {
  unsigned u = __builtin_bit_cast(unsigned, f);
  u += 0x7FFFu + ((u >> 16) & 1u);          // RNE
  return (unsigned short)(u >> 16);
}
__device__ __forceinline__ float bf2f(unsigned short u) {
  return __uint_as_float(((unsigned)u) << 16);
}

// ---------------- prepass 1: K f32 -> bf16 ----------------
__global__ void cvt_k_kernel(const float* __restrict__ k, unsigned short* __restrict__ kbf) {
  int i = blockIdx.x * 256 + threadIdx.x;   // i < B*T*D/4
  float4 f = ((const float4*)k)[i];
  ushort4 o = { f2bf(f.x), f2bf(f.y), f2bf(f.z), f2bf(f.w) };
  ((ushort4*)kbf)[i] = o;
}

// ---------------- prepass 2: V f32 [b][s][d] -> bf16 [b][d][s] ----------------
__global__ void tv_kernel(const float* __restrict__ v, unsigned short* __restrict__ vt) {
  __shared__ float tile[64][65];
  const int b = blockIdx.z, d0 = blockIdx.y * 64, s0 = blockIdx.x * 64;
  const int tid = threadIdx.x;
#pragma unroll
  for (int u = 0; u < 4; ++u) {
    int flat = u * 256 + tid; int r = flat >> 4, c4 = flat & 15;
    float4 f = *(const float4*)(v + ((size_t)b * T_DIM + s0 + r) * D_DIM + d0 + c4 * 4);
    tile[r][c4 * 4 + 0] = f.x; tile[r][c4 * 4 + 1] = f.y;
    tile[r][c4 * 4 + 2] = f.z; tile[r][c4 * 4 + 3] = f.w;
  }
  __syncthreads();
#pragma unroll
  for (int u = 0; u < 4; ++u) {
    int flat = u * 256 + tid; int dr = flat >> 4, sq = flat & 15;
    ushort4 o = { f2bf(tile[sq * 4 + 0][dr]), f2bf(tile[sq * 4 + 1][dr]),
                  f2bf(tile[sq * 4 + 2][dr]), f2bf(tile[sq * 4 + 3][dr]) };
    *(ushort4*)(vt + ((size_t)b * D_DIM + d0 + dr) * T_DIM + s0 + sq * 4) = o;
  }
}

// ---------------- prepass 3: Qeff f32 -> bf16 (roll + mix + scale folded) ----------------
__global__ void qeff_kernel(const float* __restrict__ q, const float* __restrict__ modep,
                            unsigned short* __restrict__ qbf) {
  int i = blockIdx.x * 256 + threadIdx.x;   // 8-element chunk id, i < B*T*D/8
  int row = i >> 4, c8 = i & 15;
  const float* qr = q + (size_t)row * D_DIM;
  float e[9];
  float4 f0 = *(const float4*)(qr + c8 * 8);
  float4 f1 = *(const float4*)(qr + c8 * 8 + 4);
  e[0] = f0.x; e[1] = f0.y; e[2] = f0.z; e[3] = f0.w;
  e[4] = f1.x; e[5] = f1.y; e[6] = f1.z; e[7] = f1.w;
  e[8] = qr[(c8 * 8 + 8) & 127];
  const float alpha = 1.f / (1.f + __expf(-modep[0]));
  const float scale = 0.08838834764831845f;
  const float ca = -alpha * scale, cb = (1.f - alpha) * scale;
  short8 o;
#pragma unroll
  for (int j = 0; j < 8; ++j) o[j] = (short)f2bf(ca * e[j] + cb * e[j + 1]);
  *(short8*)(qbf + (size_t)i * 8) = o;
}

// ---------------- main: split-KV flash attention, 1 wave / block ----------------
// block owns rows [c*32, c*32+32), KV tiles [seg*segt, min(nt, seg*segt+segt)), tile=64 rows.
__global__ __launch_bounds__(64) void attn_kernel(
    const unsigned short* __restrict__ qbf, const unsigned short* __restrict__ kbf,
    const unsigned short* __restrict__ vt, float* __restrict__ out,
    unsigned short* __restrict__ po, float* __restrict__ ml, int segt)
{
  const int lane = threadIdx.x;
  const int t16 = lane & 15, g = lane >> 4;
  const int b = blockIdx.x;                  // linear_wgid % 8 == b -> batch pinned to XCD
  const int c = 63 - (int)blockIdx.y;        // big chunks dispatch first
  const int seg = blockIdx.z;
  const int nt = (c >> 1) + 1;               // causal tiles for this chunk
  const int G = segt << 1;
  const int nseg = c / G + 1;                // == ceil(nt/segt)
  if (seg >= nseg) return;
  const int t0 = seg * segt;
  const int t1 = min(nt, t0 + segt);

  __shared__ char psm[2 * 16 * 144];         // P staging, per-wave (4.6 KB)

  // Qeff fragments: A-layout, lane(t16,g) holds Q[t16][dd*32+g*8 ..+8]
  short8 qf[2][4];
#pragma unroll
  for (int mt = 0; mt < 2; ++mt) {
    const unsigned short* qr = qbf + ((size_t)b * T_DIM + c * 32 + mt * 16 + t16) * D_DIM + g * 8;
#pragma unroll
    for (int dd = 0; dd < 4; ++dd) qf[mt][dd] = *(const short8*)(qr + dd * 32);
  }

  f32x4 acc[2][8];
#pragma unroll
  for (int mt = 0; mt < 2; ++mt)
#pragma unroll
    for (int dt = 0; dt < 8; ++dt) acc[mt][dt] = (f32x4){0.f, 0.f, 0.f, 0.f};
  float mrun[2][4], lrun[2][4];
#pragma unroll
  for (int mt = 0; mt < 2; ++mt)
#pragma unroll
    for (int r = 0; r < 4; ++r) { mrun[mt][r] = -1e30f; lrun[mt][r] = 0.f; }

  for (int kt = t0; kt < t1; ++kt) {
    const int kv0 = kt * 64;

    // ---- S = Qeff . K^T : K fragments direct from global (L2-resident) ----
    f32x4 sj[2][4];
#pragma unroll
    for (int jt = 0; jt < 4; ++jt) {
      const unsigned short* kr = kbf + ((size_t)b * T_DIM + kv0 + jt * 16 + t16) * D_DIM + g * 8;
      f32x4 s0 = (f32x4){0.f, 0.f, 0.f, 0.f};
      f32x4 s1 = (f32x4){0.f, 0.f, 0.f, 0.f};
#pragma unroll
      for (int dd = 0; dd < 4; ++dd) {
        short8 kf = *(const short8*)(kr + dd * 32);
        s0 = __builtin_amdgcn_mfma_f32_16x16x32_bf16(qf[0][dd], kf, s0, 0, 0, 0);
        s1 = __builtin_amdgcn_mfma_f32_16x16x32_bf16(qf[1][dd], kf, s1, 0, 0, 0);
      }
      sj[0][jt] = s0; sj[1][jt] = s1;
    }

    const bool lastt = (kt == nt - 1);
#pragma unroll
    for (int mt = 0; mt < 2; ++mt) {
      // causal mask: only the chunk's final tile can be partial
      if (lastt) {
#pragma unroll
        for (int jt = 0; jt < 4; ++jt) {
          int sg = kv0 + jt * 16 + t16;
#pragma unroll
          for (int r = 0; r < 4; ++r) {
            int tg = c * 32 + mt * 16 + 4 * g + r;
            if (sg > tg) sj[mt][jt][r] = -1e30f;
          }
        }
      }
      // online softmax (row stats live in C-layout: row = 4g+r, reduce over t16 group)
      float tm[4];
#pragma unroll
      for (int r = 0; r < 4; ++r)
        tm[r] = fmaxf(fmaxf(sj[mt][0][r], sj[mt][1][r]), fmaxf(sj[mt][2][r], sj[mt][3][r]));
#pragma unroll
      for (int r = 0; r < 4; ++r) {
        tm[r] = fmaxf(tm[r], __shfl_xor(tm[r], 1));
        tm[r] = fmaxf(tm[r], __shfl_xor(tm[r], 2));
        tm[r] = fmaxf(tm[r], __shfl_xor(tm[r], 4));
        tm[r] = fmaxf(tm[r], __shfl_xor(tm[r], 8));
      }
      float corr[4], rs[4];
#pragma unroll
      for (int r = 0; r < 4; ++r) {
        float mnew = fmaxf(mrun[mt][r], tm[r]);
        corr[r] = __expf(mrun[mt][r] - mnew);
        mrun[mt][r] = mnew;
        rs[r] = 0.f;
      }
#pragma unroll
      for (int jt = 0; jt < 4; ++jt)
#pragma unroll
        for (int r = 0; r < 4; ++r) {
          float p = __expf(sj[mt][jt][r] - mrun[mt][r]);
          sj[mt][jt][r] = p;
          rs[r] += p;
        }
#pragma unroll
      for (int r = 0; r < 4; ++r) {
        rs[r] += __shfl_xor(rs[r], 1);
        rs[r] += __shfl_xor(rs[r], 2);
        rs[r] += __shfl_xor(rs[r], 4);
        rs[r] += __shfl_xor(rs[r], 8);
        lrun[mt][r] = lrun[mt][r] * corr[r] + rs[r];
      }
#pragma unroll
      for (int dt = 0; dt < 8; ++dt)
#pragma unroll
        for (int r = 0; r < 4; ++r) acc[mt][dt][r] *= corr[r];
      // P -> per-wave LDS (C-layout -> row-major [t][s]); same-wave, in-order DS
      char* pbase = psm + mt * (16 * 144);
#pragma unroll
      for (int jt = 0; jt < 4; ++jt)
#pragma unroll
        for (int r = 0; r < 4; ++r)
          *(unsigned short*)(pbase + (4 * g + r) * 144 + (jt * 16 + t16) * 2) = f2bf(sj[mt][jt][r]);
    }

    // ---- O += P . V : V^T fragments direct from global ----
#pragma unroll
    for (int k0 = 0; k0 < 2; ++k0) {
      short8 pf0 = *(const short8*)(psm + t16 * 144 + k0 * 64 + g * 16);
      short8 pf1 = *(const short8*)(psm + 16 * 144 + t16 * 144 + k0 * 64 + g * 16);
#pragma unroll
      for (int dt = 0; dt < 8; ++dt) {
        const unsigned short* vr = vt + ((size_t)b * D_DIM + dt * 16 + t16) * T_DIM + kv0 + k0 * 32 + g * 8;
        short8 vf = *(const short8*)vr;
        acc[0][dt] = __builtin_amdgcn_mfma_f32_16x16x32_bf16(pf0, vf, acc[0][dt], 0, 0, 0);
        acc[1][dt] = __builtin_amdgcn_mfma_f32_16x16x32_bf16(pf1, vf, acc[1][dt], 0, 0, 0);
      }
    }
  }

  // ---- epilogue ----
  if (nseg == 1) {
    // single segment: write normalized output directly
#pragma unroll
    for (int mt = 0; mt < 2; ++mt)
#pragma unroll
      for (int r = 0; r < 4; ++r) {
        float inv = 1.0f / lrun[mt][r];
#pragma unroll
        for (int dt = 0; dt < 8; ++dt)
          out[((size_t)b * T_DIM + c * 32 + mt * 16 + 4 * g + r) * D_DIM + dt * 16 + t16] =
              acc[mt][dt][r] * inv;
      }
  } else {
    // partial: unnormalized O (bf16) + running m,l
    const int a = c / G, rm = c % G;
    const int A = 64 / G;
    const int npb = 64 + G * (A * (A - 1) / 2);
    const int slot = b * npb + c + G * (a * (a - 1) / 2) + a * rm + seg;  // R3: + seg
    unsigned short* pob = po + (size_t)slot * 4096;
#pragma unroll
    for (int mt = 0; mt < 2; ++mt)
#pragma unroll
      for (int r = 0; r < 4; ++r)
#pragma unroll
        for (int dt = 0; dt < 8; ++dt)
          pob[(mt * 16 + 4 * g + r) * 128 + dt * 16 + t16] = f2bf(acc[mt][dt][r]);
    if (t16 == 0) {
#pragma unroll
      for (int mt = 0; mt < 2; ++mt)
#pragma unroll
        for (int r = 0; r < 4; ++r) {
          ml[(size_t)slot * 64 + mt * 16 + 4 * g + r] = mrun[mt][r];
          ml[(size_t)slot * 64 + 32 + mt * 16 + 4 * g + r] = lrun[mt][r];
        }
    }
  }
}

// ---------------- combine partials (chunks with nseg >= 2) ----------------
__global__ __launch_bounds__(256) void combine_kernel(
    const unsigned short* __restrict__ po, const float* __restrict__ ml,
    float* __restrict__ out, int segt)
{
  const int tid = threadIdx.x;
  const int b = blockIdx.x;                  // same XCD as the writers -> L2-hit reads
  const int G = segt << 1;
  const int c = G + (int)blockIdx.y;
  const int nseg = c / G + 1;
  const int a = c / G, rm = c % G;
  const int A = 64 / G;
  const int npb = 64 + G * (A * (A - 1) / 2);
  const int slot0 = b * npb + c + G * (a * (a - 1) / 2) + a * rm;

  __shared__ float w[32][8];
  if (tid < 32) {
    float M = -1e30f;
    for (int s = 0; s < nseg; ++s)
      M = fmaxf(M, ml[(size_t)(slot0 + s) * 64 + tid]);
    float L = 0.f;
    for (int s = 0; s < nseg; ++s) {
      float e = __expf(ml[(size_t)(slot0 + s) * 64 + tid] - M);
      w[tid][s] = e;
      L += e * ml[(size_t)(slot0 + s) * 64 + 32 + tid];
    }
    float invL = 1.f / L;
    for (int s = 0; s < nseg; ++s) w[tid][s] *= invL;
  }
  __syncthreads();

#pragma unroll
  for (int it = 0; it < 2; ++it) {
    int vid = it * 256 + tid;                // 512 short8-chunks = 32 rows x 16
    int rr = vid >> 4, ch = vid & 15;
    float o[8] = {0.f, 0.f, 0.f, 0.f, 0.f, 0.f, 0.f, 0.f};
    for (int s = 0; s < nseg; ++s) {
      short8 pv = *(const short8*)(po + (size_t)(slot0 + s) * 4096 + rr * 128 + ch * 8);
      float ws = w[rr][s];
#pragma unroll
      for (int j = 0; j < 8; ++j) o[j] += ws * bf2f((unsigned short)pv[j]);
    }
    float* dst = out + ((size_t)b * T_DIM + c * 32 + rr) * D_DIM + ch * 8;
    *(float4*)(dst) = (float4){o[0], o[1], o[2], o[3]};
    *(float4*)(dst + 4) = (float4){o[4], o[5], o[6], o[7]};
  }
}

extern "C" void kernel_launch(void* const* d_in, const int* in_sizes, int n_in,
                              void* d_out, int out_size, void* d_ws, size_t ws_size,
                              hipStream_t stream) {
  const float* q = (const float*)d_in[0];
  const float* k = (const float*)d_in[1];
  const float* v = (const float*)d_in[2];
  // d_in[3] = mask (causal tril, hardcoded)
  const float* mode = (const float*)d_in[4];
  float* out = (float*)d_out;

  char* ws = (char*)d_ws;
  unsigned short* kbf = (unsigned short*)(ws);                 // 4,194,304 B
  unsigned short* vtb = (unsigned short*)(ws + 4194304);       // 4,194,304 B
  unsigned short* qbf = (unsigned short*)(ws + 8388608);       // 4,194,304 B
  unsigned short* po  = (unsigned short*)(ws + 12582912);      // 2304*4096*2 = 18,874,368 B
  float*          ml  = (float*)(ws + 31457280);               // 2304*64*4  =    589,824 B
  // total 32,047,104 B

  const bool split = ws_size >= 32047104ULL;
  const int segt = split ? 4 : 32;

  cvt_k_kernel<<<2048, 256, 0, stream>>>(k, kbf);
  tv_kernel<<<dim3(T_DIM / 64, D_DIM / 64, B_DIM), 256, 0, stream>>>(v, vtb);
  qeff_kernel<<<1024, 256, 0, stream>>>(q, mode, qbf);
  attn_kernel<<<dim3(B_DIM, 64, split ? 8 : 1), 64, 0, stream>>>(qbf, kbf, vtb, out, po, ml, segt);
  if (split)
    combine_kernel<<<dim3(B_DIM, 56), 256, 0, stream>>>(po, ml, out, segt);
}

// Round 4
// 63.382 us; speedup vs baseline: 1.5708x; 1.5708x over previous
//
#include <hip/hip_runtime.h>
#include <hip/hip_bf16.h>
#include <cstdint>
#include <cstddef>

// B=8, T=2048, D=128 causal dual-mode attention.
// logits = Qeff . K^T with Qeff[t][d] = -alpha*scale*q[t][d] + (1-alpha)*scale*q[t][(d+1)%D]
// (feature-roll moved from K onto Q), then causal softmax, then @V.
//
// R4: 4-wave (256t) blocks, 128 q-rows/block; KV tile 64 staged to LDS via
// global_load_lds (dbuf, 1 barrier/step, XOR-swizzled both sides); split-KV
// segt=8 with flat partial slots + combine.

typedef __attribute__((ext_vector_type(8))) short short8;
typedef __attribute__((ext_vector_type(4))) float f32x4;

#define T_DIM 2048
#define D_DIM 128
#define B_DIM 8
#define MAXSEG 4

__device__ __forceinline__ unsigned short f2bf(float f) {
  unsigned u = __builtin_bit_cast(unsigned, f);
  u += 0x7FFFu + ((u >> 16) & 1u);          // RNE
  return (unsigned short)(u >> 16);
}
__device__ __forceinline__ float bf2f(unsigned short u) {
  return __uint_as_float(((unsigned)u) << 16);
}
__device__ __forceinline__ void gload_lds16(const void* g, void* l) {
  __builtin_amdgcn_global_load_lds(
      (const __attribute__((address_space(1))) unsigned int*)g,
      (__attribute__((address_space(3))) unsigned int*)l, 16, 0, 0);
}

// ---------------- prepass A: K->bf16 and Qeff->bf16 (fused) ----------------
__global__ void prep_kq(const float* __restrict__ k, const float* __restrict__ q,
                        const float* __restrict__ modep,
                        unsigned short* __restrict__ kbf, unsigned short* __restrict__ qbf) {
  int i = blockIdx.x * 256 + threadIdx.x;     // 8-elem chunk id, i < B*T*D/8
  // K convert
  float4 ka = ((const float4*)k)[2 * i], kb = ((const float4*)k)[2 * i + 1];
  short8 ko = { (short)f2bf(ka.x), (short)f2bf(ka.y), (short)f2bf(ka.z), (short)f2bf(ka.w),
                (short)f2bf(kb.x), (short)f2bf(kb.y), (short)f2bf(kb.z), (short)f2bf(kb.w) };
  ((short8*)kbf)[i] = ko;
  // Qeff: roll + mix + scale folded
  int row = i >> 4, c8 = i & 15;
  const float* qr = q + (size_t)row * D_DIM;
  float e[9];
  float4 f0 = *(const float4*)(qr + c8 * 8);
  float4 f1 = *(const float4*)(qr + c8 * 8 + 4);
  e[0] = f0.x; e[1] = f0.y; e[2] = f0.z; e[3] = f0.w;
  e[4] = f1.x; e[5] = f1.y; e[6] = f1.z; e[7] = f1.w;
  e[8] = qr[(c8 * 8 + 8) & 127];
  const float alpha = 1.f / (1.f + __expf(-modep[0]));
  const float scale = 0.08838834764831845f;
  const float ca = -alpha * scale, cb = (1.f - alpha) * scale;
  short8 o;
#pragma unroll
  for (int j = 0; j < 8; ++j) o[j] = (short)f2bf(ca * e[j] + cb * e[j + 1]);
  ((short8*)qbf)[i] = o;
}

// ---------------- prepass B: V f32 [b][s][d] -> bf16 [b][d][s] ----------------
__global__ void tv_kernel(const float* __restrict__ v, unsigned short* __restrict__ vt) {
  __shared__ float tile[64][65];
  const int b = blockIdx.z, d0 = blockIdx.y * 64, s0 = blockIdx.x * 64;
  const int tid = threadIdx.x;
#pragma unroll
  for (int u = 0; u < 4; ++u) {
    int flat = u * 256 + tid; int r = flat >> 4, c4 = flat & 15;
    float4 f = *(const float4*)(v + ((size_t)b * T_DIM + s0 + r) * D_DIM + d0 + c4 * 4);
    tile[r][c4 * 4 + 0] = f.x; tile[r][c4 * 4 + 1] = f.y;
    tile[r][c4 * 4 + 2] = f.z; tile[r][c4 * 4 + 3] = f.w;
  }
  __syncthreads();
#pragma unroll
  for (int u = 0; u < 4; ++u) {
    int flat = u * 256 + tid; int dr = flat >> 4, sq = flat & 15;
    ushort4 o = { f2bf(tile[sq * 4 + 0][dr]), f2bf(tile[sq * 4 + 1][dr]),
                  f2bf(tile[sq * 4 + 2][dr]), f2bf(tile[sq * 4 + 3][dr]) };
    *(ushort4*)(vt + ((size_t)b * D_DIM + d0 + dr) * T_DIM + s0 + sq * 4) = o;
  }
}

// ---------------- main attention ----------------
// LDS 80KB: Kbuf[2] 2x16KB | Vbuf[2] 2x16KB | P per-wave 4x4KB
__global__ __launch_bounds__(256, 2) void attn_kernel(
    const unsigned short* __restrict__ qbf, const unsigned short* __restrict__ kbf,
    const unsigned short* __restrict__ vt, float* __restrict__ out,
    unsigned short* __restrict__ po, float* __restrict__ ml, int segt)
{
  __shared__ uint4 smem4[5120];               // 80 KB
  char* smem = (char*)smem4;
  const int tid = threadIdx.x;
  const int w = tid >> 6, lane = tid & 63;
  const int t16 = lane & 15, g = lane >> 4;
  const int b = blockIdx.x;                   // linear%8==b -> batch pinned to XCD
  const int qc = blockIdx.y, seg = blockIdx.z;
  const int nt = 2 * qc + 2;
  const int nseg = (nt + segt - 1) / segt;
  if (seg >= nseg) return;
  const int t0 = seg * segt;
  const int t1 = min(nt, t0 + segt);
  const int qb = qc * 128 + w * 32;           // wave's first q-row
  const int tdiag = qb >> 6;                  // tile containing this wave's diagonal

  char* pw = smem + 65536 + w * 4096;         // per-wave P [2mt][16][128B], swizzled
  const unsigned short* kbase = kbf + (size_t)b * T_DIM * D_DIM;
  const unsigned short* vbase = vt + (size_t)b * D_DIM * T_DIM;

  // ---- Qeff fragments (A-layout: row=t16, k=dd*32+g*8+i) ----
  short8 qf[2][4];
#pragma unroll
  for (int mt = 0; mt < 2; ++mt) {
    const unsigned short* qr = qbf + ((size_t)b * T_DIM + qb + mt * 16 + t16) * D_DIM + g * 8;
#pragma unroll
    for (int dd = 0; dd < 4; ++dd) qf[mt][dd] = *(const short8*)(qr + dd * 32);
  }

  f32x4 acc[2][8];
#pragma unroll
  for (int mt = 0; mt < 2; ++mt)
#pragma unroll
    for (int dt = 0; dt < 8; ++dt) acc[mt][dt] = (f32x4){0.f, 0.f, 0.f, 0.f};
  float mrun[2][4], lrun[2][4];
#pragma unroll
  for (int mt = 0; mt < 2; ++mt)
#pragma unroll
    for (int r = 0; r < 4; ++r) { mrun[mt][r] = -1e30f; lrun[mt][r] = 0.f; }

  // ---- async stage of one KV tile into buffer cur (wave w does its quarter) ----
  // K LDS layout: [s 0..63][128B row] with byte col ^= (s&7)<<4 (inverse-swz source).
  // V LDS layout: [d 0..127][64 cols=128B] with byte col ^= (d&7)<<4.
  auto stage = [&](int cur, int kt) {
    const int kv0 = kt * 64;
    char* kb = smem + cur * 16384;
    char* vb = smem + 32768 + cur * 16384;
#pragma unroll
    for (int u = 0; u < 4; ++u) {
      int s_loc = w * 16 + u * 4 + (lane >> 4);
      int slot = (lane & 15) ^ (s_loc & 7);
      gload_lds16(kbase + (size_t)(kv0 + s_loc) * D_DIM + slot * 8,
                  kb + w * 4096 + u * 1024);
    }
    const int vslot = (lane & 7) ^ ((lane >> 3) & 7);
#pragma unroll
    for (int u = 0; u < 4; ++u) {
      int d_loc = w * 32 + u * 8 + (lane >> 3);
      gload_lds16(vbase + (size_t)d_loc * T_DIM + kv0 + vslot * 8,
                  vb + w * 4096 + u * 1024);
    }
  };

  stage(0, t0);
  __syncthreads();                            // drains vmcnt before first compute
  int cur = 0;

  for (int kt = t0; kt < t1; ++kt) {
    if (kt + 1 < t1) stage(cur ^ 1, kt + 1);  // prefetch next tile (issues only)

    if (kt <= tdiag) {
      const int kv0 = kt * 64;
      char* kb = smem + cur * 16384;
      char* vb = smem + 32768 + cur * 16384;

      // ---- S = Qeff . K^T ----
      f32x4 sj[2][4];
#pragma unroll
      for (int jt = 0; jt < 4; ++jt) {
        int s = jt * 16 + t16;
        int rb = s * 256, swz = (s & 7) << 4;
        f32x4 s0 = (f32x4){0.f, 0.f, 0.f, 0.f};
        f32x4 s1 = (f32x4){0.f, 0.f, 0.f, 0.f};
#pragma unroll
        for (int dd = 0; dd < 4; ++dd) {
          short8 kf = *(const short8*)(kb + ((rb + dd * 64 + g * 16) ^ swz));
          s0 = __builtin_amdgcn_mfma_f32_16x16x32_bf16(qf[0][dd], kf, s0, 0, 0, 0);
          s1 = __builtin_amdgcn_mfma_f32_16x16x32_bf16(qf[1][dd], kf, s1, 0, 0, 0);
        }
        sj[0][jt] = s0; sj[1][jt] = s1;
      }

      const bool needmask = (kt == tdiag);
#pragma unroll
      for (int mt = 0; mt < 2; ++mt) {
        if (needmask) {
#pragma unroll
          for (int jt = 0; jt < 4; ++jt) {
            int sg = kv0 + jt * 16 + t16;
#pragma unroll
            for (int r = 0; r < 4; ++r) {
              int tg = qb + mt * 16 + 4 * g + r;
              if (sg > tg) sj[mt][jt][r] = -1e30f;
            }
          }
        }
        // online softmax (row = 4g+r; reduce over 16-lane t16 group)
        float tm[4];
#pragma unroll
        for (int r = 0; r < 4; ++r)
          tm[r] = fmaxf(fmaxf(sj[mt][0][r], sj[mt][1][r]), fmaxf(sj[mt][2][r], sj[mt][3][r]));
#pragma unroll
        for (int r = 0; r < 4; ++r) {
          tm[r] = fmaxf(tm[r], __shfl_xor(tm[r], 1));
          tm[r] = fmaxf(tm[r], __shfl_xor(tm[r], 2));
          tm[r] = fmaxf(tm[r], __shfl_xor(tm[r], 4));
          tm[r] = fmaxf(tm[r], __shfl_xor(tm[r], 8));
        }
        float corr[4], rs[4];
#pragma unroll
        for (int r = 0; r < 4; ++r) {
          float mnew = fmaxf(mrun[mt][r], tm[r]);
          corr[r] = __expf(mrun[mt][r] - mnew);
          mrun[mt][r] = mnew;
          rs[r] = 0.f;
        }
#pragma unroll
        for (int jt = 0; jt < 4; ++jt)
#pragma unroll
          for (int r = 0; r < 4; ++r) {
            float p = __expf(sj[mt][jt][r] - mrun[mt][r]);
            sj[mt][jt][r] = p;
            rs[r] += p;
          }
#pragma unroll
        for (int r = 0; r < 4; ++r) {
          rs[r] += __shfl_xor(rs[r], 1);
          rs[r] += __shfl_xor(rs[r], 2);
          rs[r] += __shfl_xor(rs[r], 4);
          rs[r] += __shfl_xor(rs[r], 8);
          lrun[mt][r] = lrun[mt][r] * corr[r] + rs[r];
        }
#pragma unroll
        for (int dt = 0; dt < 8; ++dt)
#pragma unroll
          for (int r = 0; r < 4; ++r) acc[mt][dt][r] *= corr[r];
        // P -> per-wave LDS (C-layout -> [row][col] swizzled)
        char* pb = pw + mt * 2048;
#pragma unroll
        for (int jt = 0; jt < 4; ++jt)
#pragma unroll
          for (int r = 0; r < 4; ++r) {
            int rloc = 4 * g + r;
            *(unsigned short*)(pb + rloc * 128 + ((2 * (jt * 16 + t16)) ^ ((rloc & 7) << 4))) =
                f2bf(sj[mt][jt][r]);
          }
      }

      // ---- O += P . V ----
#pragma unroll
      for (int k0 = 0; k0 < 2; ++k0) {
        short8 pf0 = *(const short8*)(pw + t16 * 128 + ((k0 * 64 + g * 16) ^ ((t16 & 7) << 4)));
        short8 pf1 = *(const short8*)(pw + 2048 + t16 * 128 + ((k0 * 64 + g * 16) ^ ((t16 & 7) << 4)));
#pragma unroll
        for (int dt = 0; dt < 8; ++dt) {
          int d = dt * 16 + t16;
          short8 vf = *(const short8*)(vb + d * 128 + (((k0 * 4 + g) << 4) ^ ((d & 7) << 4)));
          acc[0][dt] = __builtin_amdgcn_mfma_f32_16x16x32_bf16(pf0, vf, acc[0][dt], 0, 0, 0);
          acc[1][dt] = __builtin_amdgcn_mfma_f32_16x16x32_bf16(pf1, vf, acc[1][dt], 0, 0, 0);
        }
      }
    }

    __syncthreads();                          // prefetch done + all reads of cur done
    cur ^= 1;
  }

  // ---- epilogue ----
  if (nseg == 1) {
#pragma unroll
    for (int mt = 0; mt < 2; ++mt)
#pragma unroll
      for (int r = 0; r < 4; ++r) {
        float inv = 1.0f / lrun[mt][r];
#pragma unroll
        for (int dt = 0; dt < 8; ++dt)
          out[((size_t)b * T_DIM + qc * 128 + w * 32 + mt * 16 + 4 * g + r) * D_DIM + dt * 16 + t16] =
              acc[mt][dt][r] * inv;
      }
  } else {
    const int slot = (b * 16 + qc) * MAXSEG + seg;   // flat slots, 512 total
    unsigned short* pob = po + (size_t)slot * 16384;
#pragma unroll
    for (int mt = 0; mt < 2; ++mt)
#pragma unroll
      for (int r = 0; r < 4; ++r) {
        int rb = w * 32 + mt * 16 + 4 * g + r;
#pragma unroll
        for (int dt = 0; dt < 8; ++dt)
          pob[rb * 128 + dt * 16 + t16] = f2bf(acc[mt][dt][r]);
      }
    if (t16 == 0) {
#pragma unroll
      for (int mt = 0; mt < 2; ++mt)
#pragma unroll
        for (int r = 0; r < 4; ++r) {
          int rb = w * 32 + mt * 16 + 4 * g + r;
          ml[(size_t)slot * 256 + rb] = mrun[mt][r];
          ml[(size_t)slot * 256 + 128 + rb] = lrun[mt][r];
        }
    }
  }
}

// ---------------- combine partials (qc >= 4) ----------------
__global__ __launch_bounds__(256) void combine_kernel(
    const unsigned short* __restrict__ po, const float* __restrict__ ml,
    float* __restrict__ out, int segt)
{
  const int tid = threadIdx.x;
  const int b = blockIdx.x;
  const int qc = 4 + (int)blockIdx.y;
  const int nt = 2 * qc + 2;
  const int nseg = (nt + segt - 1) / segt;
  const int slot0 = (b * 16 + qc) * MAXSEG;

  __shared__ float wgt[128][MAXSEG];
  if (tid < 128) {
    float M = -1e30f;
    for (int s = 0; s < nseg; ++s)
      M = fmaxf(M, ml[(size_t)(slot0 + s) * 256 + tid]);
    float L = 0.f;
    for (int s = 0; s < nseg; ++s) {
      float e = __expf(ml[(size_t)(slot0 + s) * 256 + tid] - M);
      wgt[tid][s] = e;
      L += e * ml[(size_t)(slot0 + s) * 256 + 128 + tid];
    }
    float invL = 1.f / L;
    for (int s = 0; s < nseg; ++s) wgt[tid][s] *= invL;
  }
  __syncthreads();

#pragma unroll
  for (int it = 0; it < 8; ++it) {
    int vid = it * 256 + tid;                 // 2048 = 128 rows x 16 chunks
    int r = vid >> 4, ch = vid & 15;
    float o[8] = {0.f, 0.f, 0.f, 0.f, 0.f, 0.f, 0.f, 0.f};
    for (int s = 0; s < nseg; ++s) {
      short8 pv = *(const short8*)(po + (size_t)(slot0 + s) * 16384 + r * 128 + ch * 8);
      float ws = wgt[r][s];
#pragma unroll
      for (int j = 0; j < 8; ++j) o[j] += ws * bf2f((unsigned short)pv[j]);
    }
    float* dst = out + ((size_t)b * T_DIM + qc * 128 + r) * D_DIM + ch * 8;
    *(float4*)(dst) = (float4){o[0], o[1], o[2], o[3]};
    *(float4*)(dst + 4) = (float4){o[4], o[5], o[6], o[7]};
  }
}

extern "C" void kernel_launch(void* const* d_in, const int* in_sizes, int n_in,
                              void* d_out, int out_size, void* d_ws, size_t ws_size,
                              hipStream_t stream) {
  const float* q = (const float*)d_in[0];
  const float* k = (const float*)d_in[1];
  const float* v = (const float*)d_in[2];
  // d_in[3] = mask (causal tril, hardcoded)
  const float* mode = (const float*)d_in[4];
  float* out = (float*)d_out;

  char* ws = (char*)d_ws;
  unsigned short* kbf = (unsigned short*)(ws);                 //  4 MB
  unsigned short* vtb = (unsigned short*)(ws + 4194304);       //  4 MB
  unsigned short* qbf = (unsigned short*)(ws + 8388608);       //  4 MB
  unsigned short* po  = (unsigned short*)(ws + 12582912);      // 512*32KB = 16 MB
  float*          ml  = (float*)(ws + 29360128);               // 512*1KB  = 0.5 MB
  // total 29,884,416 B

  const bool split = ws_size >= 29884416ULL;
  const int segt = split ? 8 : 32;             // segt=32 -> nseg==1 everywhere

  prep_kq<<<1024, 256, 0, stream>>>(k, q, mode, kbf, qbf);
  tv_kernel<<<dim3(T_DIM / 64, D_DIM / 64, B_DIM), 256, 0, stream>>>(v, vtb);
  attn_kernel<<<dim3(B_DIM, 16, split ? MAXSEG : 1), 256, 0, stream>>>(
      qbf, kbf, vtb, out, po, ml, segt);
  if (split)
    combine_kernel<<<dim3(B_DIM, 12), 256, 0, stream>>>(po, ml, out, segt);
}

// Round 5
// 58.598 us; speedup vs baseline: 1.6991x; 1.0816x over previous
//
#include <hip/hip_runtime.h>
#include <hip/hip_bf16.h>
#include <cstdint>
#include <cstddef>

// B=8, T=2048, D=128 causal dual-mode attention.
// logits = Qeff . K^T with Qeff[t][d] = -alpha*scale*q[t][d] + (1-alpha)*scale*q[t][(d+1)%D]
// (feature-roll moved from K onto Q), then causal softmax, then @V.
//
// R5: 2-wave (128t) blocks, 64 q-rows/block, KVBLK=64 single-buffered in 36KB LDS
// (4 blocks/CU co-resident -> 4 independent barriers per CU hide each other's
// latency). Fused single prepass. Split-KV segt=8 + combine.

typedef __attribute__((ext_vector_type(8))) short short8;
typedef __attribute__((ext_vector_type(4))) float f32x4;

#define T_DIM 2048
#define D_DIM 128
#define B_DIM 8
#define MAXSEG 4

__device__ __forceinline__ unsigned short f2bf(float f) {
  unsigned u = __builtin_bit_cast(unsigned, f);
  u += 0x7FFFu + ((u >> 16) & 1u);          // RNE
  return (unsigned short)(u >> 16);
}
__device__ __forceinline__ float bf2f(unsigned short u) {
  return __uint_as_float(((unsigned)u) << 16);
}
__device__ __forceinline__ void gload_lds16(const void* g, void* l) {
  __builtin_amdgcn_global_load_lds(
      (const __attribute__((address_space(1))) unsigned int*)g,
      (__attribute__((address_space(3))) unsigned int*)l, 16, 0, 0);
}

// ---------------- fused prepass: K->bf16, Qeff->bf16, V->bf16 transposed ----------------
// grid (8 batches, 32 s-chunks of 64 rows) x 256 thr; x=batch -> XCD-pinned writes.
__global__ __launch_bounds__(256) void prep_all(
    const float* __restrict__ q, const float* __restrict__ k, const float* __restrict__ v,
    const float* __restrict__ modep,
    unsigned short* __restrict__ qbf, unsigned short* __restrict__ kbf,
    unsigned short* __restrict__ vt)
{
  __shared__ unsigned short tile[64 * 136];   // V rows as bf16, pitch 136 shorts
  const int b = blockIdx.x, s0 = blockIdx.y * 64;
  const int tid = threadIdx.x;
  const float alpha = 1.f / (1.f + __expf(-modep[0]));
  const float scale = 0.08838834764831845f;
  const float ca = -alpha * scale, cb = (1.f - alpha) * scale;

#pragma unroll
  for (int u = 0; u < 4; ++u) {
    int c = u * 256 + tid;                    // 1024 chunks = 64 rows x 16
    int r = c >> 4, c8 = c & 15;
    size_t row = (size_t)b * T_DIM + s0 + r;
    // K convert
    float4 ka = *(const float4*)(k + row * D_DIM + c8 * 8);
    float4 kb2 = *(const float4*)(k + row * D_DIM + c8 * 8 + 4);
    short8 ko = { (short)f2bf(ka.x), (short)f2bf(ka.y), (short)f2bf(ka.z), (short)f2bf(ka.w),
                  (short)f2bf(kb2.x), (short)f2bf(kb2.y), (short)f2bf(kb2.z), (short)f2bf(kb2.w) };
    *(short8*)(kbf + row * D_DIM + c8 * 8) = ko;
    // Qeff (roll + mix + scale)
    const float* qr = q + row * D_DIM;
    float e[9];
    float4 f0 = *(const float4*)(qr + c8 * 8);
    float4 f1 = *(const float4*)(qr + c8 * 8 + 4);
    e[0] = f0.x; e[1] = f0.y; e[2] = f0.z; e[3] = f0.w;
    e[4] = f1.x; e[5] = f1.y; e[6] = f1.z; e[7] = f1.w;
    e[8] = qr[(c8 * 8 + 8) & 127];
    short8 qo;
#pragma unroll
    for (int j = 0; j < 8; ++j) qo[j] = (short)f2bf(ca * e[j] + cb * e[j + 1]);
    *(short8*)(qbf + row * D_DIM + c8 * 8) = qo;
    // V -> bf16 into LDS tile
    float4 va = *(const float4*)(v + row * D_DIM + c8 * 8);
    float4 vb2 = *(const float4*)(v + row * D_DIM + c8 * 8 + 4);
    short8 vo = { (short)f2bf(va.x), (short)f2bf(va.y), (short)f2bf(va.z), (short)f2bf(va.w),
                  (short)f2bf(vb2.x), (short)f2bf(vb2.y), (short)f2bf(vb2.z), (short)f2bf(vb2.w) };
    *(short8*)(tile + r * 136 + c8 * 8) = vo;
  }
  __syncthreads();
  // transposed write: vt[b][d][s0 + 0..63]
#pragma unroll
  for (int u = 0; u < 8; ++u) {
    int c = u * 256 + tid;                    // 2048 = 128 d x 16 s-quads
    int d = c >> 4, sq = c & 15;
    ushort4 o = { tile[(sq * 4 + 0) * 136 + d], tile[(sq * 4 + 1) * 136 + d],
                  tile[(sq * 4 + 2) * 136 + d], tile[(sq * 4 + 3) * 136 + d] };
    *(ushort4*)(vt + ((size_t)b * D_DIM + d) * T_DIM + s0 + sq * 4) = o;
  }
}

// ---------------- main attention ----------------
// LDS 36KB: K [64][256B] swz | V [128][128B] swz | P per-wave 2KB ([16][128B] swz)
__global__ __launch_bounds__(128, 2) void attn_kernel(
    const unsigned short* __restrict__ qbf, const unsigned short* __restrict__ kbf,
    const unsigned short* __restrict__ vt, float* __restrict__ out,
    unsigned short* __restrict__ po, float* __restrict__ ml, int segt)
{
  __shared__ uint4 smem4[2304];               // 36 KB
  char* smem = (char*)smem4;
  const int tid = threadIdx.x;
  const int w = tid >> 6, lane = tid & 63;
  const int t16 = lane & 15, g = lane >> 4;
  const int b = blockIdx.x;                   // linear%8==b -> batch pinned to XCD
  const int qc = blockIdx.y, seg = blockIdx.z;
  const int nt = qc + 1;                      // causal 64-row tiles for this 64-row chunk
  const int nseg = (nt + segt - 1) / segt;
  if (seg >= nseg) return;
  const int t0 = seg * segt;
  const int t1 = min(nt, t0 + segt);
  const int qb = qc * 64 + w * 32;            // wave's first q-row

  char* kb = smem;                            // 16 KB
  char* vb = smem + 16384;                    // 16 KB
  char* pw = smem + 32768 + w * 2048;         // per-wave P, 2 KB
  const unsigned short* kbase = kbf + (size_t)b * T_DIM * D_DIM;
  const unsigned short* vbase = vt + (size_t)b * D_DIM * T_DIM;

  // ---- Qeff fragments (A-layout: row=t16, k=dd*32+g*8+i) ----
  short8 qf[2][4];
#pragma unroll
  for (int mt = 0; mt < 2; ++mt) {
    const unsigned short* qr = qbf + ((size_t)b * T_DIM + qb + mt * 16 + t16) * D_DIM + g * 8;
#pragma unroll
    for (int dd = 0; dd < 4; ++dd) qf[mt][dd] = *(const short8*)(qr + dd * 32);
  }

  f32x4 acc[2][8];
#pragma unroll
  for (int mt = 0; mt < 2; ++mt)
#pragma unroll
    for (int dt = 0; dt < 8; ++dt) acc[mt][dt] = (f32x4){0.f, 0.f, 0.f, 0.f};
  float mrun[2][4], lrun[2][4];
#pragma unroll
  for (int mt = 0; mt < 2; ++mt)
#pragma unroll
    for (int r = 0; r < 4; ++r) { mrun[mt][r] = -1e30f; lrun[mt][r] = 0.f; }

  for (int kt = t0; kt < t1; ++kt) {
    const int kv0 = kt * 64;
    __syncthreads();                          // everyone done reading previous tile
    // ---- stage K tile: wave w rows w*32..+31; LDS row s gets units p = src p^(s&7) ----
#pragma unroll
    for (int u = 0; u < 8; ++u) {
      int s_loc = w * 32 + u * 4 + (lane >> 4);
      int slot = (lane & 15) ^ (s_loc & 7);
      gload_lds16(kbase + (size_t)(kv0 + s_loc) * D_DIM + slot * 8,
                  kb + w * 8192 + u * 1024);
    }
    // ---- stage V tile: wave w d-rows w*64..+63 ----
#pragma unroll
    for (int u = 0; u < 8; ++u) {
      int d_loc = w * 64 + u * 8 + (lane >> 3);
      int vslot = (lane & 7) ^ (d_loc & 7);
      gload_lds16(vbase + (size_t)d_loc * T_DIM + kv0 + vslot * 8,
                  vb + w * 8192 + u * 1024);
    }
    __syncthreads();                          // drain (vmcnt0 before barrier)

    // ---- S = Qeff . K^T ----
    f32x4 sj[2][4];
#pragma unroll
    for (int jt = 0; jt < 4; ++jt) {
      int s = jt * 16 + t16;
      int rb = s * 256, swz = (s & 7) << 4;
      f32x4 s0 = (f32x4){0.f, 0.f, 0.f, 0.f};
      f32x4 s1 = (f32x4){0.f, 0.f, 0.f, 0.f};
#pragma unroll
      for (int dd = 0; dd < 4; ++dd) {
        short8 kf = *(const short8*)(kb + ((rb + dd * 64 + g * 16) ^ swz));
        s0 = __builtin_amdgcn_mfma_f32_16x16x32_bf16(qf[0][dd], kf, s0, 0, 0, 0);
        s1 = __builtin_amdgcn_mfma_f32_16x16x32_bf16(qf[1][dd], kf, s1, 0, 0, 0);
      }
      sj[0][jt] = s0; sj[1][jt] = s1;
    }

    const bool needmask = (kt == nt - 1);     // only the diagonal tile is partial
#pragma unroll
    for (int mt = 0; mt < 2; ++mt) {
      if (needmask) {
#pragma unroll
        for (int jt = 0; jt < 4; ++jt) {
          int sg = kv0 + jt * 16 + t16;
#pragma unroll
          for (int r = 0; r < 4; ++r) {
            int tg = qb + mt * 16 + 4 * g + r;
            if (sg > tg) sj[mt][jt][r] = -1e30f;
          }
        }
      }
      // online softmax (row = 4g+r; reduce over 16-lane t16 group)
      float tm[4];
#pragma unroll
      for (int r = 0; r < 4; ++r)
        tm[r] = fmaxf(fmaxf(sj[mt][0][r], sj[mt][1][r]), fmaxf(sj[mt][2][r], sj[mt][3][r]));
#pragma unroll
      for (int r = 0; r < 4; ++r) {
        tm[r] = fmaxf(tm[r], __shfl_xor(tm[r], 1));
        tm[r] = fmaxf(tm[r], __shfl_xor(tm[r], 2));
        tm[r] = fmaxf(tm[r], __shfl_xor(tm[r], 4));
        tm[r] = fmaxf(tm[r], __shfl_xor(tm[r], 8));
      }
      float corr[4], rs[4];
#pragma unroll
      for (int r = 0; r < 4; ++r) {
        float mnew = fmaxf(mrun[mt][r], tm[r]);
        corr[r] = __expf(mrun[mt][r] - mnew);
        mrun[mt][r] = mnew;
        rs[r] = 0.f;
      }
#pragma unroll
      for (int jt = 0; jt < 4; ++jt)
#pragma unroll
        for (int r = 0; r < 4; ++r) {
          float p = __expf(sj[mt][jt][r] - mrun[mt][r]);
          sj[mt][jt][r] = p;
          rs[r] += p;
        }
#pragma unroll
      for (int r = 0; r < 4; ++r) {
        rs[r] += __shfl_xor(rs[r], 1);
        rs[r] += __shfl_xor(rs[r], 2);
        rs[r] += __shfl_xor(rs[r], 4);
        rs[r] += __shfl_xor(rs[r], 8);
        lrun[mt][r] = lrun[mt][r] * corr[r] + rs[r];
      }
#pragma unroll
      for (int dt = 0; dt < 8; ++dt)
#pragma unroll
        for (int r = 0; r < 4; ++r) acc[mt][dt][r] *= corr[r];

      // P -> per-wave LDS (C-layout -> [row][col] swizzled); same-wave in-order DS
#pragma unroll
      for (int jt = 0; jt < 4; ++jt)
#pragma unroll
        for (int r = 0; r < 4; ++r) {
          int rloc = 4 * g + r;
          *(unsigned short*)(pw + rloc * 128 + ((2 * (jt * 16 + t16)) ^ ((rloc & 7) << 4))) =
              f2bf(sj[mt][jt][r]);
        }

      // ---- O[mt] += P . V ----
#pragma unroll
      for (int k0 = 0; k0 < 2; ++k0) {
        short8 pf = *(const short8*)(pw + t16 * 128 + ((k0 * 64 + g * 16) ^ ((t16 & 7) << 4)));
#pragma unroll
        for (int dt = 0; dt < 8; ++dt) {
          int d = dt * 16 + t16;
          short8 vf = *(const short8*)(vb + d * 128 + (((k0 * 4 + g) << 4) ^ ((d & 7) << 4)));
          acc[mt][dt] = __builtin_amdgcn_mfma_f32_16x16x32_bf16(pf, vf, acc[mt][dt], 0, 0, 0);
        }
      }
    }
  }

  // ---- epilogue ----
  if (nseg == 1) {
#pragma unroll
    for (int mt = 0; mt < 2; ++mt)
#pragma unroll
      for (int r = 0; r < 4; ++r) {
        float inv = 1.0f / lrun[mt][r];
#pragma unroll
        for (int dt = 0; dt < 8; ++dt)
          out[((size_t)b * T_DIM + qb + mt * 16 + 4 * g + r) * D_DIM + dt * 16 + t16] =
              acc[mt][dt][r] * inv;
      }
  } else {
    const int slot = (b * 32 + qc) * MAXSEG + seg;   // flat, 1024 slots
    unsigned short* pob = po + (size_t)slot * 8192;  // 64 rows x 128
#pragma unroll
    for (int mt = 0; mt < 2; ++mt)
#pragma unroll
      for (int r = 0; r < 4; ++r) {
        int rb = w * 32 + mt * 16 + 4 * g + r;
#pragma unroll
        for (int dt = 0; dt < 8; ++dt)
          pob[rb * 128 + dt * 16 + t16] = f2bf(acc[mt][dt][r]);
      }
    if (t16 == 0) {
#pragma unroll
      for (int mt = 0; mt < 2; ++mt)
#pragma unroll
        for (int r = 0; r < 4; ++r) {
          int rb = w * 32 + mt * 16 + 4 * g + r;
          ml[(size_t)slot * 128 + rb] = mrun[mt][r];
          ml[(size_t)slot * 128 + 64 + rb] = lrun[mt][r];
        }
    }
  }
}

// ---------------- combine partials (qc >= 8 when segt=8) ----------------
__global__ __launch_bounds__(256) void combine_kernel(
    const unsigned short* __restrict__ po, const float* __restrict__ ml,
    float* __restrict__ out, int segt)
{
  const int tid = threadIdx.x;
  const int b = blockIdx.x;
  const int qc = segt + (int)blockIdx.y;
  const int nt = qc + 1;
  const int nseg = (nt + segt - 1) / segt;
  const int slot0 = (b * 32 + qc) * MAXSEG;

  __shared__ float wgt[64][MAXSEG];
  if (tid < 64) {
    float M = -1e30f;
    for (int s = 0; s < nseg; ++s)
      M = fmaxf(M, ml[(size_t)(slot0 + s) * 128 + tid]);
    float L = 0.f;
    for (int s = 0; s < nseg; ++s) {
      float e = __expf(ml[(size_t)(slot0 + s) * 128 + tid] - M);
      wgt[tid][s] = e;
      L += e * ml[(size_t)(slot0 + s) * 128 + 64 + tid];
    }
    float invL = 1.f / L;
    for (int s = 0; s < nseg; ++s) wgt[tid][s] *= invL;
  }
  __syncthreads();

#pragma unroll
  for (int it = 0; it < 4; ++it) {
    int vid = it * 256 + tid;                 // 1024 = 64 rows x 16 chunks
    int r = vid >> 4, ch = vid & 15;
    float o[8] = {0.f, 0.f, 0.f, 0.f, 0.f, 0.f, 0.f, 0.f};
    for (int s = 0; s < nseg; ++s) {
      short8 pv = *(const short8*)(po + (size_t)(slot0 + s) * 8192 + r * 128 + ch * 8);
      float ws = wgt[r][s];
#pragma unroll
      for (int j = 0; j < 8; ++j) o[j] += ws * bf2f((unsigned short)pv[j]);
    }
    float* dst = out + ((size_t)b * T_DIM + qc * 64 + r) * D_DIM + ch * 8;
    *(float4*)(dst) = (float4){o[0], o[1], o[2], o[3]};
    *(float4*)(dst + 4) = (float4){o[4], o[5], o[6], o[7]};
  }
}

extern "C" void kernel_launch(void* const* d_in, const int* in_sizes, int n_in,
                              void* d_out, int out_size, void* d_ws, size_t ws_size,
                              hipStream_t stream) {
  const float* q = (const float*)d_in[0];
  const float* k = (const float*)d_in[1];
  const float* v = (const float*)d_in[2];
  // d_in[3] = mask (causal tril, hardcoded)
  const float* mode = (const float*)d_in[4];
  float* out = (float*)d_out;

  char* ws = (char*)d_ws;
  unsigned short* qbf = (unsigned short*)(ws);                 //  4 MB
  unsigned short* kbf = (unsigned short*)(ws + 4194304);       //  4 MB
  unsigned short* vtb = (unsigned short*)(ws + 8388608);       //  4 MB
  unsigned short* po  = (unsigned short*)(ws + 12582912);      // 1024*16KB = 16 MB
  float*          ml  = (float*)(ws + 29360128);               // 1024*512B = 0.5 MB
  // total 29,884,416 B

  const bool split = ws_size >= 29884416ULL;
  const int segt = split ? 8 : 32;             // segt=32 -> nseg==1 everywhere

  prep_all<<<dim3(B_DIM, T_DIM / 64), 256, 0, stream>>>(q, k, v, mode, qbf, kbf, vtb);
  attn_kernel<<<dim3(B_DIM, 32, split ? MAXSEG : 1), 128, 0, stream>>>(
      qbf, kbf, vtb, out, po, ml, segt);
  if (split)
    combine_kernel<<<dim3(B_DIM, 24), 256, 0, stream>>>(po, ml, out, segt);
}